// Round 5
// baseline (165.208 us; speedup 1.0000x reference)
//
#include <hip/hip_runtime.h>
#include <hip/hip_bf16.h>

#define NHEAD 8
#define SEQ   2048
#define HD    64
#define EMB   512
#define NTYPE 10
#define JSPLIT 2

#define QKV_NT (3 * EMB / 64)          // 24 n-tiles
#define QKV_MT (SEQ / 64)              // 32 m-tiles
#define QKV_BLOCKS (QKV_NT * QKV_MT)   // 768
#define PACK_BLOCKS (SEQ * SEQ / 4 / 256)  // 4096

typedef unsigned short u16;
typedef __attribute__((ext_vector_type(8))) short short8;
typedef __attribute__((ext_vector_type(4))) float float4v;

union F8 { short8 v; uint4 u4; u16 us[8]; };

__device__ __forceinline__ float bf2f(u16 u){
  union { unsigned u; float f; } w; w.u = ((unsigned)u) << 16; return w.f;
}
__device__ __forceinline__ u16 f2bf(float f){
  union { float f; unsigned u; } w; w.f = f;
  unsigned u = w.u;
  u += 0x7fffu + ((u >> 16) & 1u);   // RNE
  return (u16)(u >> 16);
}
__device__ __forceinline__ unsigned pk2(float a, float b){
  return (unsigned)f2bf(a) | ((unsigned)f2bf(b) << 16);
}
__device__ __forceinline__ uint4 pk8(float4 a, float4 b){
  uint4 p; p.x = pk2(a.x, a.y); p.y = pk2(a.z, a.w);
           p.z = pk2(b.x, b.y); p.w = pk2(b.z, b.w);
  return p;
}

// ---------------------------------------------------------------- K1: QKV projection (fp32 direct) + eid pack
// blocks [0,768): 64x64-tile GEMM  C = A*W^T (+bias)(*scale), reg-staged fp32->bf16,
//                 register double-buffer prefetch. 3 blocks/CU for latency hiding.
// blocks [768, 768+4096): eid int32 -> u8 pack.
__global__ __launch_bounds__(256) void fused_prep_gemm(
    const float* __restrict__ q, const float* __restrict__ k, const float* __restrict__ v,
    const float* __restrict__ ipw, const float* __restrict__ ipb, const int* __restrict__ eid,
    u16* __restrict__ Qs, u16* __restrict__ Kb, u16* __restrict__ Vb,
    unsigned* __restrict__ eidp)
{
  const int b = blockIdx.x;
  const int t = threadIdx.x;

  if (b >= QKV_BLOCKS) {                       // ---- eid pack path
    const int i = (b - QKV_BLOCKS) * 256 + t;
    int4 vv = ((const int4*)eid)[i];
    eidp[i] = (unsigned)(vv.x & 0xff) | ((unsigned)(vv.y & 0xff) << 8) |
              ((unsigned)(vv.z & 0xff) << 16) | ((unsigned)(vv.w & 0xff) << 24);
    return;
  }

  __shared__ u16 As[64][40];                   // padded: reg-staged, no gload_lds constraint
  __shared__ u16 Bs[64][40];

  const int nt = b % QKV_NT, mt = b / QKV_NT;
  const int n0 = nt * 64, m0 = mt * 64;
  const int z = n0 >> 9;                       // 0=q,1=k,2=v (64-tiles never cross 512)
  const float* A = (z == 0) ? q : (z == 1) ? k : v;
  const float scale = (z == 0) ? 0.125f : 1.0f;

  const int w = t >> 6, lane = t & 63, lr = lane & 15, lg = lane >> 4;
  const int wm = w >> 1, wn = w & 1;
  const int srow = t >> 2, kb = (t & 3) * 8;

  float4v acc[2][2];
#pragma unroll
  for (int mi = 0; mi < 2; mi++)
#pragma unroll
    for (int ni = 0; ni < 2; ni++) acc[mi][ni] = (float4v){0.f, 0.f, 0.f, 0.f};

  const float* pa = A   + (size_t)(m0 + srow) * EMB + kb;
  const float* pw = ipw + (size_t)(n0 + srow) * EMB + kb;

  float4 a0 = *(const float4*)pa, a1 = *(const float4*)(pa + 4);
  float4 b0 = *(const float4*)pw, b1 = *(const float4*)(pw + 4);

  for (int k0 = 0; k0 < EMB; k0 += 32) {
    *(uint4*)&As[srow][kb] = pk8(a0, a1);
    *(uint4*)&Bs[srow][kb] = pk8(b0, b1);
    __syncthreads();
    if (k0 + 32 < EMB) {                       // prefetch next K-tile (hides under MFMA)
      a0 = *(const float4*)(pa + k0 + 32); a1 = *(const float4*)(pa + k0 + 36);
      b0 = *(const float4*)(pw + k0 + 32); b1 = *(const float4*)(pw + k0 + 36);
    }
    F8 af[2], bf_[2];
#pragma unroll
    for (int mi = 0; mi < 2; mi++)
      af[mi].u4 = *(const uint4*)&As[wm * 32 + mi * 16 + lr][lg * 8];
#pragma unroll
    for (int ni = 0; ni < 2; ni++)
      bf_[ni].u4 = *(const uint4*)&Bs[wn * 32 + ni * 16 + lr][lg * 8];
#pragma unroll
    for (int mi = 0; mi < 2; mi++)
#pragma unroll
      for (int ni = 0; ni < 2; ni++)
        acc[mi][ni] = __builtin_amdgcn_mfma_f32_16x16x32_bf16(af[mi].v, bf_[ni].v, acc[mi][ni], 0, 0, 0);
    __syncthreads();
  }

  u16* O = (z == 0) ? Qs : ((z == 1) ? Kb : Vb);
#pragma unroll
  for (int mi = 0; mi < 2; mi++) {
#pragma unroll
    for (int ni = 0; ni < 2; ni++) {
      const int n = n0 + wn * 32 + ni * 16 + lr;
      const int e = n & 511, h = e >> 6, d = e & 63;
      const float bb = ipb[n];
      const int mb = m0 + wm * 32 + mi * 16 + lg * 4;
      if (z < 2) {
#pragma unroll
        for (int r = 0; r < 4; r++)
          O[((size_t)h * SEQ + mb + r) * HD + d] = f2bf((acc[mi][ni][r] + bb) * scale);
      } else {
        ushort4 pk;
        pk.x = f2bf(acc[mi][ni][0] + bb); pk.y = f2bf(acc[mi][ni][1] + bb);
        pk.z = f2bf(acc[mi][ni][2] + bb); pk.w = f2bf(acc[mi][ni][3] + bb);
        *(ushort4*)(O + ((size_t)(h * HD + d)) * SEQ + mb) = pk;   // V^T layout [h][d][m]
      }
    }
  }
}

// ---------------------------------------------------------------- K2: flash attention with edge bias
// grid: x = 32 i-tiles (64 rows), y = 8 heads, z = 2 j-chunks (1024 j each)
// Vb is TRANSPOSED: [h][d][j].
// T14 async-STAGE: next tile's K/V/eid prefetched to regs during compute, ds_write after barrier.
// eidt columns XOR-swizzled by lg; T5 setprio around MFMA clusters.
__global__ __launch_bounds__(256) void attn_kernel(
    const u16* __restrict__ Qs, const u16* __restrict__ Kb, const u16* __restrict__ Vb,
    const unsigned char* __restrict__ eidp, const float* __restrict__ EK,
    float* __restrict__ Upart, float* __restrict__ mpart, float* __restrict__ lpart)
{
  __shared__ u16 Kt[64][72];            // K tile [j][d]
  __shared__ u16 Vt[64][72];            // V tile transposed [d][j]
  __shared__ u16 Pl[4][16][72];         // per-wave P [i_local][j_local]
  __shared__ unsigned char eidt[64][64];// col-swizzled: col' = col ^ (((row>>2)&3)<<4)
  __shared__ float tsl[64][13];         // type scores per row (+1 pad)
  __shared__ float ekl[NTYPE][64];
  __shared__ float mrow[64], lrow[64], frow[64];

  const int t = threadIdx.x;
  const int wave = t >> 6, lane = t & 63, lr = lane & 15, lg = lane >> 4;
  const int i0 = blockIdx.x * 64;
  const int h  = blockIdx.y;
  const int z  = blockIdx.z;

  for (int i = t; i < NTYPE * 64; i += 256) ekl[i >> 6][i & 63] = EK[i];
  if (t < 64) { mrow[t] = -1e30f; lrow[t] = 0.f; }
  __syncthreads();

  // type scores ts[row][type] = q_scaled[row] . EK[type]
  {
    const int row = t >> 2, tt = t & 3;
    const u16* qr = Qs + ((size_t)h * SEQ + i0 + row) * HD;
    float a0 = 0.f, a1 = 0.f, a2 = 0.f;
    for (int d0 = 0; d0 < HD; d0 += 8) {
      uint4 qq = *(const uint4*)(qr + d0);
      const u16* qu = (const u16*)&qq;
#pragma unroll
      for (int e = 0; e < 8; e++) {
        float qf = bf2f(qu[e]);
        a0 += qf * ekl[tt][d0 + e];
        a1 += qf * ekl[tt + 4][d0 + e];
        a2 += qf * ekl[(tt < 2) ? (tt + 8) : 8][d0 + e];
      }
    }
    tsl[row][tt] = a0; tsl[row][tt + 4] = a1;
    if (tt < 2) tsl[row][tt + 8] = a2;
  }

  // Q fragments (A operand), held in regs all iterations
  F8 qf[2];
#pragma unroll
  for (int kc = 0; kc < 2; kc++)
    qf[kc].u4 = *(const uint4*)(Qs + ((size_t)h * SEQ + i0 + wave * 16 + lr) * HD + kc * 32 + lg * 8);

  float4v ao[4];
#pragma unroll
  for (int d = 0; d < 4; d++) ao[d] = (float4v){0.f, 0.f, 0.f, 0.f};

  const int srow = t >> 2, sdc = (t & 3) * 16;
  const int sec = sdc ^ (((t >> 4) & 3) << 4);          // swizzled eidt col
  const int jbase = z * (SEQ / JSPLIT);
  const int NT = (SEQ / JSPLIT) / 64;

  uint4 kp0, kp1, vp0, vp1, ep0;
  {
    const u16* kp = Kb + ((size_t)h * SEQ + jbase + srow) * HD + sdc;
    kp0 = *(const uint4*)kp; kp1 = *(const uint4*)(kp + 8);
    const u16* vp = Vb + ((size_t)(h * HD + srow)) * SEQ + jbase + sdc;
    vp0 = *(const uint4*)vp; vp1 = *(const uint4*)(vp + 8);
    ep0 = *(const uint4*)(eidp + (size_t)(i0 + srow) * SEQ + jbase + sdc);
    *(uint4*)&Kt[srow][sdc] = kp0; *(uint4*)&Kt[srow][sdc + 8] = kp1;
    *(uint4*)&Vt[srow][sdc] = vp0; *(uint4*)&Vt[srow][sdc + 8] = vp1;
    *(uint4*)&eidt[srow][sec] = ep0;
  }

  for (int jt = 0; jt < NT; jt++) {
    __syncthreads();                               // tile jt staged

    if (jt + 1 < NT) {                             // T14: issue next tile's loads
      const int jn = jbase + (jt + 1) * 64;
      const u16* kp = Kb + ((size_t)h * SEQ + jn + srow) * HD + sdc;
      kp0 = *(const uint4*)kp; kp1 = *(const uint4*)(kp + 8);
      const u16* vp = Vb + ((size_t)(h * HD + srow)) * SEQ + jn + sdc;
      vp0 = *(const uint4*)vp; vp1 = *(const uint4*)(vp + 8);
      ep0 = *(const uint4*)(eidp + (size_t)(i0 + srow) * SEQ + jn + sdc);
    }

    // ---- S = Q K^T
    float4v sacc[4];
#pragma unroll
    for (int c = 0; c < 4; c++) sacc[c] = (float4v){0.f, 0.f, 0.f, 0.f};
    __builtin_amdgcn_s_setprio(1);
#pragma unroll
    for (int kc = 0; kc < 2; kc++) {
#pragma unroll
      for (int c = 0; c < 4; c++) {
        F8 kf; kf.u4 = *(const uint4*)&Kt[c * 16 + lr][kc * 32 + lg * 8];
        sacc[c] = __builtin_amdgcn_mfma_f32_16x16x32_bf16(qf[kc].v, kf.v, sacc[c], 0, 0, 0);
      }
    }
    __builtin_amdgcn_s_setprio(0);

    // ---- edge bias + online softmax
    float pv_[4][4];
    float rmax[4] = {-1e30f, -1e30f, -1e30f, -1e30f};
#pragma unroll
    for (int c = 0; c < 4; c++) {
      const int ec = ((c ^ lg) << 4) + lr;
#pragma unroll
      for (int r = 0; r < 4; r++) {
        const int row = wave * 16 + lg * 4 + r;
        float s = sacc[c][r] + tsl[row][eidt[row][ec]];
        pv_[c][r] = s;
        rmax[r] = fmaxf(rmax[r], s);
      }
    }
#pragma unroll
    for (int mm = 1; mm < 16; mm <<= 1) {
#pragma unroll
      for (int r = 0; r < 4; r++) rmax[r] = fmaxf(rmax[r], __shfl_xor(rmax[r], mm));
    }
    float mnew[4], fct[4], rsum[4] = {0.f, 0.f, 0.f, 0.f};
#pragma unroll
    for (int r = 0; r < 4; r++) {
      const int row = wave * 16 + lg * 4 + r;
      const float mo = mrow[row];
      mnew[r] = fmaxf(mo, rmax[r]);
      fct[r] = __expf(mo - mnew[r]);
    }
#pragma unroll
    for (int c = 0; c < 4; c++) {
#pragma unroll
      for (int r = 0; r < 4; r++) {
        float p = __expf(pv_[c][r] - mnew[r]);
        pv_[c][r] = p;
        rsum[r] += p;
      }
    }
#pragma unroll
    for (int mm = 1; mm < 16; mm <<= 1) {
#pragma unroll
      for (int r = 0; r < 4; r++) rsum[r] += __shfl_xor(rsum[r], mm);
    }
    if (lr == 0) {
#pragma unroll
      for (int r = 0; r < 4; r++) {
        const int row = wave * 16 + lg * 4 + r;
        mrow[row] = mnew[r];
        lrow[row] = lrow[row] * fct[r] + rsum[r];
        frow[row] = fct[r];
      }
    }
#pragma unroll
    for (int c = 0; c < 4; c++) {
#pragma unroll
      for (int r = 0; r < 4; r++)
        Pl[wave][lg * 4 + r][c * 16 + lr] = f2bf(pv_[c][r]);
    }
    const float fo = frow[wave * 16 + lr];
#pragma unroll
    for (int d = 0; d < 4; d++) {
#pragma unroll
      for (int r = 0; r < 4; r++) ao[d][r] *= fo;
    }
    // ---- O^T += V^T P^T
    __builtin_amdgcn_s_setprio(1);
#pragma unroll
    for (int kc = 0; kc < 2; kc++) {
      F8 pf; pf.u4 = *(const uint4*)&Pl[wave][lr][kc * 32 + lg * 8];
#pragma unroll
      for (int db = 0; db < 4; db++) {
        F8 vf; vf.u4 = *(const uint4*)&Vt[db * 16 + lr][kc * 32 + lg * 8];
        ao[db] = __builtin_amdgcn_mfma_f32_16x16x32_bf16(vf.v, pf.v, ao[db], 0, 0, 0);
      }
    }
    __builtin_amdgcn_s_setprio(0);

    __syncthreads();                               // all waves done reading tile jt
    if (jt + 1 < NT) {                             // T14: write prefetched tile
      *(uint4*)&Kt[srow][sdc] = kp0; *(uint4*)&Kt[srow][sdc + 8] = kp1;
      *(uint4*)&Vt[srow][sdc] = vp0; *(uint4*)&Vt[srow][sdc + 8] = vp1;
      *(uint4*)&eidt[srow][sec] = ep0;
    }
  }

  // ---- write partials (unnormalized U, m, l)
  {
    const size_t base = (((size_t)z * NHEAD + h) * SEQ + i0) * HD;
#pragma unroll
    for (int db = 0; db < 4; db++) {
#pragma unroll
      for (int r = 0; r < 4; r++) {
        const int d = db * 16 + lg * 4 + r;
        const int n = wave * 16 + lr;
        Upart[base + (size_t)n * HD + d] = ao[db][r];
      }
    }
    __syncthreads();
    if (t < 64) {
      mpart[((size_t)z * NHEAD + h) * SEQ + i0 + t] = mrow[t];
      lpart[((size_t)z * NHEAD + h) * SEQ + i0 + t] = lrow[t];
    }
  }
}

// ---------------------------------------------------------------- K3: combine + out-projection
// 64x64-tile GEMM out = AO * opw^T + opb, where AO[m][e] is computed ON THE FLY from
// Upart/mpart/lpart during A-staging (combine weights precomputed per (h, row) in LDS).
__global__ __launch_bounds__(256) void combine_outproj(
    const float* __restrict__ Upart, const float* __restrict__ mpart,
    const float* __restrict__ lpart, const float* __restrict__ opw,
    const float* __restrict__ opb, float* __restrict__ out)
{
  __shared__ u16 As[64][40];
  __shared__ u16 Bs[64][40];
  __shared__ float cw0[NHEAD][64], cw1[NHEAD][64], cwi[NHEAD][64];

  const int t = threadIdx.x;
  const int n0 = blockIdx.x * 64;   // output col tile
  const int m0 = blockIdx.y * 64;   // row tile

  // combine weights per (h, local row)
  for (int idx = t; idx < NHEAD * 64; idx += 256) {
    const int hh = idx >> 6, nl = idx & 63;
    const int gn = m0 + nl;
    const float mA = mpart[((size_t)0 * NHEAD + hh) * SEQ + gn];
    const float mB = mpart[((size_t)1 * NHEAD + hh) * SEQ + gn];
    const float M = fmaxf(mA, mB);
    const float w0 = __expf(mA - M), w1 = __expf(mB - M);
    const float Ls = w0 * lpart[((size_t)0 * NHEAD + hh) * SEQ + gn] +
                     w1 * lpart[((size_t)1 * NHEAD + hh) * SEQ + gn];
    cw0[hh][nl] = w0; cw1[hh][nl] = w1; cwi[hh][nl] = 1.0f / Ls;
  }
  __syncthreads();

  const int w = t >> 6, lane = t & 63, lr = lane & 15, lg = lane >> 4;
  const int wm = w >> 1, wn = w & 1;
  const int srow = t >> 2, kb = (t & 3) * 8;

  float4v acc[2][2];
#pragma unroll
  for (int mi = 0; mi < 2; mi++)
#pragma unroll
    for (int ni = 0; ni < 2; ni++) acc[mi][ni] = (float4v){0.f, 0.f, 0.f, 0.f};

  const float* pw = opw + (size_t)(n0 + srow) * EMB + kb;

  // prologue loads for k0 = 0
  int hcur = kb >> 6, dcur = kb & 63;
  const float* pu0 = Upart + (((size_t)0 * NHEAD + hcur) * SEQ + m0 + srow) * HD + dcur;
  const float* pu1 = Upart + (((size_t)1 * NHEAD + hcur) * SEQ + m0 + srow) * HD + dcur;
  float4 u00 = *(const float4*)pu0, u01 = *(const float4*)(pu0 + 4);
  float4 u10 = *(const float4*)pu1, u11 = *(const float4*)(pu1 + 4);
  float4 b0 = *(const float4*)pw, b1 = *(const float4*)(pw + 4);

  for (int k0 = 0; k0 < EMB; k0 += 32) {
    // combine -> bf16 A tile
    {
      const float w0 = cw0[hcur][srow], w1 = cw1[hcur][srow], wi = cwi[hcur][srow];
      float4 c0, c1;
      c0.x = (u00.x * w0 + u10.x * w1) * wi; c0.y = (u00.y * w0 + u10.y * w1) * wi;
      c0.z = (u00.z * w0 + u10.z * w1) * wi; c0.w = (u00.w * w0 + u10.w * w1) * wi;
      c1.x = (u01.x * w0 + u11.x * w1) * wi; c1.y = (u01.y * w0 + u11.y * w1) * wi;
      c1.z = (u01.z * w0 + u11.z * w1) * wi; c1.w = (u01.w * w0 + u11.w * w1) * wi;
      *(uint4*)&As[srow][kb] = pk8(c0, c1);
      *(uint4*)&Bs[srow][kb] = pk8(b0, b1);
    }
    __syncthreads();
    if (k0 + 32 < EMB) {
      const int e = k0 + 32 + kb;
      hcur = e >> 6; dcur = e & 63;
      const float* q0 = Upart + (((size_t)0 * NHEAD + hcur) * SEQ + m0 + srow) * HD + dcur;
      const float* q1 = Upart + (((size_t)1 * NHEAD + hcur) * SEQ + m0 + srow) * HD + dcur;
      u00 = *(const float4*)q0; u01 = *(const float4*)(q0 + 4);
      u10 = *(const float4*)q1; u11 = *(const float4*)(q1 + 4);
      b0 = *(const float4*)(pw + k0 + 32); b1 = *(const float4*)(pw + k0 + 36);
    }
    F8 af[2], bf_[2];
#pragma unroll
    for (int mi = 0; mi < 2; mi++)
      af[mi].u4 = *(const uint4*)&As[wm * 32 + mi * 16 + lr][lg * 8];
#pragma unroll
    for (int ni = 0; ni < 2; ni++)
      bf_[ni].u4 = *(const uint4*)&Bs[wn * 32 + ni * 16 + lr][lg * 8];
#pragma unroll
    for (int mi = 0; mi < 2; mi++)
#pragma unroll
      for (int ni = 0; ni < 2; ni++)
        acc[mi][ni] = __builtin_amdgcn_mfma_f32_16x16x32_bf16(af[mi].v, bf_[ni].v, acc[mi][ni], 0, 0, 0);
    __syncthreads();
  }

#pragma unroll
  for (int mi = 0; mi < 2; mi++) {
#pragma unroll
    for (int ni = 0; ni < 2; ni++) {
      const int n = n0 + wn * 32 + ni * 16 + lr;
      const float bb = opb[n];
      const int mb = m0 + wm * 32 + mi * 16 + lg * 4;
#pragma unroll
      for (int r = 0; r < 4; r++)
        out[(size_t)(mb + r) * EMB + n] = acc[mi][ni][r] + bb;
    }
  }
}

// ---------------------------------------------------------------- launcher
extern "C" void kernel_launch(void* const* d_in, const int* in_sizes, int n_in,
                              void* d_out, int out_size, void* d_ws, size_t ws_size,
                              hipStream_t stream)
{
  const float* query = (const float*)d_in[0];
  const float* key_  = (const float*)d_in[1];
  const float* value = (const float*)d_in[2];
  const int*   eid   = (const int*)d_in[3];
  const float* ipw   = (const float*)d_in[4];
  const float* ipb   = (const float*)d_in[5];
  const float* opw   = (const float*)d_in[6];
  const float* opb   = (const float*)d_in[7];
  const float* ek    = (const float*)d_in[8];
  float* out = (float*)d_out;

  char* ws = (char*)d_ws;
  u16* Qs = (u16*)ws;              ws += (size_t)NHEAD * SEQ * HD * 2;
  u16* Kb = (u16*)ws;              ws += (size_t)NHEAD * SEQ * HD * 2;
  u16* Vb = (u16*)ws;              ws += (size_t)NHEAD * SEQ * HD * 2;     // transposed [h][d][j]
  unsigned char* eidp = (unsigned char*)ws; ws += (size_t)SEQ * SEQ;
  float* Upart = (float*)ws;       ws += (size_t)JSPLIT * NHEAD * SEQ * HD * 4;
  float* mpart = (float*)ws;       ws += (size_t)JSPLIT * NHEAD * SEQ * 4;
  float* lpart = (float*)ws;       ws += (size_t)JSPLIT * NHEAD * SEQ * 4;

  fused_prep_gemm<<<dim3(QKV_BLOCKS + PACK_BLOCKS), dim3(256), 0, stream>>>(
      query, key_, value, ipw, ipb, eid, Qs, Kb, Vb, (unsigned*)eidp);
  attn_kernel<<<dim3(SEQ / 64, NHEAD, JSPLIT), dim3(256), 0, stream>>>(
      Qs, Kb, Vb, eidp, ek, Upart, mpart, lpart);
  combine_outproj<<<dim3(EMB / 64, SEQ / 64), dim3(256), 0, stream>>>(
      Upart, mpart, lpart, opw, opb, out);
}

// Round 6
// 165.017 us; speedup vs baseline: 1.0012x; 1.0012x over previous
//
#include <hip/hip_runtime.h>
#include <hip/hip_bf16.h>

#define NHEAD 8
#define SEQ   2048
#define HD    64
#define EMB   512
#define NTYPE 10
#define JSPLIT 4

#define QKV_NT (3 * EMB / 64)          // 24 n-tiles
#define QKV_MT (SEQ / 64)              // 32 m-tiles
#define QKV_BLOCKS (QKV_NT * QKV_MT)   // 768
#define PACK_BLOCKS (SEQ * SEQ / 4 / 256)  // 4096

#define QSCALE 0.180336878f            // 0.125 * log2(e): exp2-domain softmax

typedef unsigned short u16;
typedef __attribute__((ext_vector_type(8))) short short8;
typedef __attribute__((ext_vector_type(4))) float float4v;

union F8 { short8 v; uint4 u4; u16 us[8]; };

__device__ __forceinline__ float bf2f(u16 u){
  union { unsigned u; float f; } w; w.u = ((unsigned)u) << 16; return w.f;
}
__device__ __forceinline__ u16 f2bf(float f){
  union { float f; unsigned u; } w; w.f = f;
  unsigned u = w.u;
  u += 0x7fffu + ((u >> 16) & 1u);   // RNE
  return (u16)(u >> 16);
}
// HW v_cvt_pk_bf16_f32 (RNE): lo -> low u16, hi -> high u16
__device__ __forceinline__ unsigned cvtpk(float lo, float hi){
  union { __hip_bfloat162 b; unsigned u; } w;
  w.b = __float22bfloat162_rn(float2{lo, hi});
  return w.u;
}
__device__ __forceinline__ uint4 pk8(float4 a, float4 b){
  uint4 p; p.x = cvtpk(a.x, a.y); p.y = cvtpk(a.z, a.w);
           p.z = cvtpk(b.x, b.y); p.w = cvtpk(b.z, b.w);
  return p;
}

// ---------------------------------------------------------------- K1: QKV projection (fp32 direct) + eid pack
// blocks [0,768): 64x64-tile GEMM  C = A*W^T (+bias)(*scale), reg-staged fp32->bf16,
//                 register double-buffer prefetch. Q scaled by QSCALE (exp2-domain).
// blocks [768, 768+4096): eid int32 -> u8 pack.
__global__ __launch_bounds__(256) void fused_prep_gemm(
    const float* __restrict__ q, const float* __restrict__ k, const float* __restrict__ v,
    const float* __restrict__ ipw, const float* __restrict__ ipb, const int* __restrict__ eid,
    u16* __restrict__ Qs, u16* __restrict__ Kb, u16* __restrict__ Vb,
    unsigned* __restrict__ eidp)
{
  const int b = blockIdx.x;
  const int t = threadIdx.x;

  if (b >= QKV_BLOCKS) {                       // ---- eid pack path
    const int i = (b - QKV_BLOCKS) * 256 + t;
    int4 vv = ((const int4*)eid)[i];
    eidp[i] = (unsigned)(vv.x & 0xff) | ((unsigned)(vv.y & 0xff) << 8) |
              ((unsigned)(vv.z & 0xff) << 16) | ((unsigned)(vv.w & 0xff) << 24);
    return;
  }

  __shared__ u16 As[64][40];
  __shared__ u16 Bs[64][40];

  const int nt = b % QKV_NT, mt = b / QKV_NT;
  const int n0 = nt * 64, m0 = mt * 64;
  const int z = n0 >> 9;                       // 0=q,1=k,2=v
  const float* A = (z == 0) ? q : (z == 1) ? k : v;
  const float scale = (z == 0) ? QSCALE : 1.0f;

  const int w = t >> 6, lane = t & 63, lr = lane & 15, lg = lane >> 4;
  const int wm = w >> 1, wn = w & 1;
  const int srow = t >> 2, kb = (t & 3) * 8;

  float4v acc[2][2];
#pragma unroll
  for (int mi = 0; mi < 2; mi++)
#pragma unroll
    for (int ni = 0; ni < 2; ni++) acc[mi][ni] = (float4v){0.f, 0.f, 0.f, 0.f};

  const float* pa = A   + (size_t)(m0 + srow) * EMB + kb;
  const float* pw = ipw + (size_t)(n0 + srow) * EMB + kb;

  float4 a0 = *(const float4*)pa, a1 = *(const float4*)(pa + 4);
  float4 b0 = *(const float4*)pw, b1 = *(const float4*)(pw + 4);

  for (int k0 = 0; k0 < EMB; k0 += 32) {
    *(uint4*)&As[srow][kb] = pk8(a0, a1);
    *(uint4*)&Bs[srow][kb] = pk8(b0, b1);
    __syncthreads();
    if (k0 + 32 < EMB) {                       // prefetch next K-tile
      a0 = *(const float4*)(pa + k0 + 32); a1 = *(const float4*)(pa + k0 + 36);
      b0 = *(const float4*)(pw + k0 + 32); b1 = *(const float4*)(pw + k0 + 36);
    }
    F8 af[2], bf_[2];
#pragma unroll
    for (int mi = 0; mi < 2; mi++)
      af[mi].u4 = *(const uint4*)&As[wm * 32 + mi * 16 + lr][lg * 8];
#pragma unroll
    for (int ni = 0; ni < 2; ni++)
      bf_[ni].u4 = *(const uint4*)&Bs[wn * 32 + ni * 16 + lr][lg * 8];
#pragma unroll
    for (int mi = 0; mi < 2; mi++)
#pragma unroll
      for (int ni = 0; ni < 2; ni++)
        acc[mi][ni] = __builtin_amdgcn_mfma_f32_16x16x32_bf16(af[mi].v, bf_[ni].v, acc[mi][ni], 0, 0, 0);
    __syncthreads();
  }

  u16* O = (z == 0) ? Qs : ((z == 1) ? Kb : Vb);
#pragma unroll
  for (int mi = 0; mi < 2; mi++) {
#pragma unroll
    for (int ni = 0; ni < 2; ni++) {
      const int n = n0 + wn * 32 + ni * 16 + lr;
      const int e = n & 511, h = e >> 6, d = e & 63;
      const float bb = ipb[n];
      const int mb = m0 + wm * 32 + mi * 16 + lg * 4;
      if (z < 2) {
#pragma unroll
        for (int r = 0; r < 4; r++)
          O[((size_t)h * SEQ + mb + r) * HD + d] = f2bf((acc[mi][ni][r] + bb) * scale);
      } else {
        ushort4 pk;
        pk.x = f2bf(acc[mi][ni][0] + bb); pk.y = f2bf(acc[mi][ni][1] + bb);
        pk.z = f2bf(acc[mi][ni][2] + bb); pk.w = f2bf(acc[mi][ni][3] + bb);
        *(ushort4*)(O + ((size_t)(h * HD + d)) * SEQ + mb) = pk;   // V^T layout [h][d][m]
      }
    }
  }
}

// ---------------------------------------------------------------- K2: flash attention with edge bias
// Swapped QK^T: S^T = mfma(K, Q) -> lane (lr,lg) owns row i=wave*16+lr,
// scores j = c*16+lg*4+r. Softmax m/l in REGISTERS; 2-level shfl reduce;
// exp2-domain (Q pre-scaled by log2e/8); eid gathered from global per-lane-row;
// P packed via v_cvt_pk_bf16_f32 + ds_write_b64. T14 reg-prefetch of K/V/eid.
// grid: x = 32 i-tiles, y = 8 heads, z = JSPLIT j-chunks. Vb TRANSPOSED [h][d][j].
__global__ __launch_bounds__(256) void attn_kernel(
    const u16* __restrict__ Qs, const u16* __restrict__ Kb, const u16* __restrict__ Vb,
    const unsigned* __restrict__ eid32, const float* __restrict__ EK,
    float* __restrict__ Upart, float* __restrict__ mpart, float* __restrict__ lpart)
{
  __shared__ u16 Kt[64][72];            // K tile [j][d]
  __shared__ u16 Vt[64][72];            // V tile transposed [d][j]
  __shared__ u16 Pl[4][16][72];         // per-wave P [i_local][j_local]
  __shared__ float tsl[64][13];         // type scores per row (+pad)
  __shared__ float ekl[NTYPE][64];

  const int t = threadIdx.x;
  const int wave = t >> 6, lane = t & 63, lr = lane & 15, lg = lane >> 4;
  const int i0 = blockIdx.x * 64;
  const int h  = blockIdx.y;
  const int z  = blockIdx.z;

  for (int i = t; i < NTYPE * 64; i += 256) ekl[i >> 6][i & 63] = EK[i];
  __syncthreads();

  // type scores ts[row][type] = q_scaled[row] . EK[type]  (exp2-domain via Q scale)
  {
    const int row = t >> 2, tt = t & 3;
    const u16* qr = Qs + ((size_t)h * SEQ + i0 + row) * HD;
    float a0 = 0.f, a1 = 0.f, a2 = 0.f;
    for (int d0 = 0; d0 < HD; d0 += 8) {
      uint4 qq = *(const uint4*)(qr + d0);
      const u16* qu = (const u16*)&qq;
#pragma unroll
      for (int e = 0; e < 8; e++) {
        float qf = bf2f(qu[e]);
        a0 += qf * ekl[tt][d0 + e];
        a1 += qf * ekl[tt + 4][d0 + e];
        a2 += qf * ekl[(tt < 2) ? (tt + 8) : 8][d0 + e];
      }
    }
    tsl[row][tt] = a0; tsl[row][tt + 4] = a1;
    if (tt < 2) tsl[row][tt + 8] = a2;
  }

  // Q fragments (B operand now), held in regs all iterations
  F8 qf[2];
#pragma unroll
  for (int kc = 0; kc < 2; kc++)
    qf[kc].u4 = *(const uint4*)(Qs + ((size_t)h * SEQ + i0 + wave * 16 + lr) * HD + kc * 32 + lg * 8);

  float4v ao[4];
#pragma unroll
  for (int d = 0; d < 4; d++) ao[d] = (float4v){0.f, 0.f, 0.f, 0.f};
  float m_i = -1e30f, l_i = 0.f;       // own-row softmax state (dup x4 across lg)

  const int srow = t >> 2, sdc = (t & 3) * 16;
  const int jbase = z * (SEQ / JSPLIT);
  const int NT = (SEQ / JSPLIT) / 64;
  const unsigned* erow = eid32 + (size_t)(i0 + wave * 16 + lr) * (SEQ / 4);

  uint4 kp0, kp1, vp0, vp1;
  unsigned ed[4], edn[4];
  {
    const u16* kp = Kb + ((size_t)h * SEQ + jbase + srow) * HD + sdc;
    kp0 = *(const uint4*)kp; kp1 = *(const uint4*)(kp + 8);
    const u16* vp = Vb + ((size_t)(h * HD + srow)) * SEQ + jbase + sdc;
    vp0 = *(const uint4*)vp; vp1 = *(const uint4*)(vp + 8);
    *(uint4*)&Kt[srow][sdc] = kp0; *(uint4*)&Kt[srow][sdc + 8] = kp1;
    *(uint4*)&Vt[srow][sdc] = vp0; *(uint4*)&Vt[srow][sdc + 8] = vp1;
    const int ej = jbase >> 2;
#pragma unroll
    for (int c = 0; c < 4; c++) ed[c] = erow[ej + c * 4 + lg];
  }

  for (int jt = 0; jt < NT; jt++) {
    __syncthreads();                               // tile jt staged (and tsl on jt==0)

    if (jt + 1 < NT) {                             // T14: issue next tile's loads
      const int jn = jbase + (jt + 1) * 64;
      const u16* kp = Kb + ((size_t)h * SEQ + jn + srow) * HD + sdc;
      kp0 = *(const uint4*)kp; kp1 = *(const uint4*)(kp + 8);
      const u16* vp = Vb + ((size_t)(h * HD + srow)) * SEQ + jn + sdc;
      vp0 = *(const uint4*)vp; vp1 = *(const uint4*)(vp + 8);
      const int ejn = jn >> 2;
#pragma unroll
      for (int c = 0; c < 4; c++) edn[c] = erow[ejn + c * 4 + lg];
    }

    // ---- S^T = mfma(K, Q): sacc[c][r] = S[i=wave*16+lr][j=c*16+lg*4+r]
    float4v sacc[4];
#pragma unroll
    for (int c = 0; c < 4; c++) sacc[c] = (float4v){0.f, 0.f, 0.f, 0.f};
#pragma unroll
    for (int kc = 0; kc < 2; kc++) {
#pragma unroll
      for (int c = 0; c < 4; c++) {
        F8 kf; kf.u4 = *(const uint4*)&Kt[c * 16 + lr][kc * 32 + lg * 8];
        sacc[c] = __builtin_amdgcn_mfma_f32_16x16x32_bf16(kf.v, qf[kc].v, sacc[c], 0, 0, 0);
      }
    }

    // ---- edge bias (byte r of ed[c] = type of score sacc[c][r]) + row max
    float rmax = -1e30f;
#pragma unroll
    for (int c = 0; c < 4; c++) {
      const unsigned e = ed[c];
#pragma unroll
      for (int r = 0; r < 4; r++) {
        const float s = sacc[c][r] + tsl[wave * 16 + lr][(e >> (r * 8)) & 0xffu];
        sacc[c][r] = s;
        rmax = fmaxf(rmax, s);
      }
    }
    rmax = fmaxf(rmax, __shfl_xor(rmax, 16));
    rmax = fmaxf(rmax, __shfl_xor(rmax, 32));
    const float mnew = fmaxf(m_i, rmax);
    const float fct = exp2f(m_i - mnew);
    float rsum = 0.f;
#pragma unroll
    for (int c = 0; c < 4; c++) {
#pragma unroll
      for (int r = 0; r < 4; r++) {
        const float p = exp2f(sacc[c][r] - mnew);
        sacc[c][r] = p;
        rsum += p;
      }
    }
    rsum += __shfl_xor(rsum, 16);
    rsum += __shfl_xor(rsum, 32);
    l_i = l_i * fct + rsum;
    m_i = mnew;

    // ---- pack P (HW cvt_pk RNE), 8B write per c (2-way bank: free)
#pragma unroll
    for (int c = 0; c < 4; c++) {
      uint2 pw;
      pw.x = cvtpk(sacc[c][0], sacc[c][1]);
      pw.y = cvtpk(sacc[c][2], sacc[c][3]);
      *(uint2*)&Pl[wave][lr][c * 16 + lg * 4] = pw;
    }
    // rescale O (fct is own-row)
#pragma unroll
    for (int db = 0; db < 4; db++) {
#pragma unroll
      for (int r = 0; r < 4; r++) ao[db][r] *= fct;
    }
    // ---- O^T += V^T P^T   (D: row=d_local, col=i_local=lr)
#pragma unroll
    for (int kc = 0; kc < 2; kc++) {
      F8 pf; pf.u4 = *(const uint4*)&Pl[wave][lr][kc * 32 + lg * 8];
#pragma unroll
      for (int db = 0; db < 4; db++) {
        F8 vf; vf.u4 = *(const uint4*)&Vt[db * 16 + lr][kc * 32 + lg * 8];
        ao[db] = __builtin_amdgcn_mfma_f32_16x16x32_bf16(vf.v, pf.v, ao[db], 0, 0, 0);
      }
    }

    __syncthreads();                               // all waves done reading tile jt
    if (jt + 1 < NT) {                             // T14: write prefetched tile
      *(uint4*)&Kt[srow][sdc] = kp0; *(uint4*)&Kt[srow][sdc + 8] = kp1;
      *(uint4*)&Vt[srow][sdc] = vp0; *(uint4*)&Vt[srow][sdc + 8] = vp1;
#pragma unroll
      for (int c = 0; c < 4; c++) ed[c] = edn[c];
    }
  }

  // ---- write partials (unnormalized U, m, l)  -- m/l in base-2 domain
  {
    const size_t base = (((size_t)z * NHEAD + h) * SEQ + i0) * HD;
#pragma unroll
    for (int db = 0; db < 4; db++) {
#pragma unroll
      for (int r = 0; r < 4; r++) {
        const int d = db * 16 + lg * 4 + r;
        const int n = wave * 16 + lr;
        Upart[base + (size_t)n * HD + d] = ao[db][r];
      }
    }
    if (lg == 0) {
      mpart[((size_t)z * NHEAD + h) * SEQ + i0 + wave * 16 + lr] = m_i;
      lpart[((size_t)z * NHEAD + h) * SEQ + i0 + wave * 16 + lr] = l_i;
    }
  }
}

// ---------------------------------------------------------------- K3: combine + out-projection
// 64x64-tile GEMM out = AO * opw^T + opb; AO combined on the fly from JSPLIT partials
// (weights w_z/Ls precomputed per (h,row) in LDS, exp2-domain).
__global__ __launch_bounds__(256) void combine_outproj(
    const float* __restrict__ Upart, const float* __restrict__ mpart,
    const float* __restrict__ lpart, const float* __restrict__ opw,
    const float* __restrict__ opb, float* __restrict__ out)
{
  __shared__ u16 As[64][40];
  __shared__ u16 Bs[64][40];
  __shared__ float cww[JSPLIT][NHEAD][64];

  const int t = threadIdx.x;
  const int n0 = blockIdx.x * 64;   // output col tile
  const int m0 = blockIdx.y * 64;   // row tile

  for (int idx = t; idx < NHEAD * 64; idx += 256) {
    const int hh = idx >> 6, nl = idx & 63;
    const int gn = m0 + nl;
    float mz[JSPLIT], wz[JSPLIT];
    float M = -1e30f;
#pragma unroll
    for (int zz = 0; zz < JSPLIT; zz++) {
      mz[zz] = mpart[((size_t)zz * NHEAD + hh) * SEQ + gn];
      M = fmaxf(M, mz[zz]);
    }
    float Ls = 0.f;
#pragma unroll
    for (int zz = 0; zz < JSPLIT; zz++) {
      wz[zz] = exp2f(mz[zz] - M);
      Ls += wz[zz] * lpart[((size_t)zz * NHEAD + hh) * SEQ + gn];
    }
    const float inv = 1.0f / Ls;
#pragma unroll
    for (int zz = 0; zz < JSPLIT; zz++) cww[zz][hh][nl] = wz[zz] * inv;
  }
  __syncthreads();

  const int w = t >> 6, lane = t & 63, lr = lane & 15, lg = lane >> 4;
  const int wm = w >> 1, wn = w & 1;
  const int srow = t >> 2, kb = (t & 3) * 8;

  float4v acc[2][2];
#pragma unroll
  for (int mi = 0; mi < 2; mi++)
#pragma unroll
    for (int ni = 0; ni < 2; ni++) acc[mi][ni] = (float4v){0.f, 0.f, 0.f, 0.f};

  const float* pw = opw + (size_t)(n0 + srow) * EMB + kb;

  int hcur = kb >> 6, dcur = kb & 63;
  float4 ua[JSPLIT][2];
#pragma unroll
  for (int zz = 0; zz < JSPLIT; zz++) {
    const float* pu = Upart + (((size_t)zz * NHEAD + hcur) * SEQ + m0 + srow) * HD + dcur;
    ua[zz][0] = *(const float4*)pu; ua[zz][1] = *(const float4*)(pu + 4);
  }
  float4 b0 = *(const float4*)pw, b1 = *(const float4*)(pw + 4);

  for (int k0 = 0; k0 < EMB; k0 += 32) {
    {
      float4 c0 = {0.f,0.f,0.f,0.f}, c1 = {0.f,0.f,0.f,0.f};
#pragma unroll
      for (int zz = 0; zz < JSPLIT; zz++) {
        const float wgt = cww[zz][hcur][srow];
        c0.x += ua[zz][0].x * wgt; c0.y += ua[zz][0].y * wgt;
        c0.z += ua[zz][0].z * wgt; c0.w += ua[zz][0].w * wgt;
        c1.x += ua[zz][1].x * wgt; c1.y += ua[zz][1].y * wgt;
        c1.z += ua[zz][1].z * wgt; c1.w += ua[zz][1].w * wgt;
      }
      *(uint4*)&As[srow][kb] = pk8(c0, c1);
      *(uint4*)&Bs[srow][kb] = pk8(b0, b1);
    }
    __syncthreads();
    if (k0 + 32 < EMB) {
      const int e = k0 + 32 + kb;
      hcur = e >> 6; dcur = e & 63;
#pragma unroll
      for (int zz = 0; zz < JSPLIT; zz++) {
        const float* pu = Upart + (((size_t)zz * NHEAD + hcur) * SEQ + m0 + srow) * HD + dcur;
        ua[zz][0] = *(const float4*)pu; ua[zz][1] = *(const float4*)(pu + 4);
      }
      b0 = *(const float4*)(pw + k0 + 32); b1 = *(const float4*)(pw + k0 + 36);
    }
    F8 af[2], bf_[2];
#pragma unroll
    for (int mi = 0; mi < 2; mi++)
      af[mi].u4 = *(const uint4*)&As[wm * 32 + mi * 16 + lr][lg * 8];
#pragma unroll
    for (int ni = 0; ni < 2; ni++)
      bf_[ni].u4 = *(const uint4*)&Bs[wn * 32 + ni * 16 + lr][lg * 8];
#pragma unroll
    for (int mi = 0; mi < 2; mi++)
#pragma unroll
      for (int ni = 0; ni < 2; ni++)
        acc[mi][ni] = __builtin_amdgcn_mfma_f32_16x16x32_bf16(af[mi].v, bf_[ni].v, acc[mi][ni], 0, 0, 0);
    __syncthreads();
  }

#pragma unroll
  for (int mi = 0; mi < 2; mi++) {
#pragma unroll
    for (int ni = 0; ni < 2; ni++) {
      const int n = n0 + wn * 32 + ni * 16 + lr;
      const float bb = opb[n];
      const int mb = m0 + wm * 32 + mi * 16 + lg * 4;
#pragma unroll
      for (int r = 0; r < 4; r++)
        out[(size_t)(mb + r) * EMB + n] = acc[mi][ni][r] + bb;
    }
  }
}

// ---------------------------------------------------------------- launcher
extern "C" void kernel_launch(void* const* d_in, const int* in_sizes, int n_in,
                              void* d_out, int out_size, void* d_ws, size_t ws_size,
                              hipStream_t stream)
{
  const float* query = (const float*)d_in[0];
  const float* key_  = (const float*)d_in[1];
  const float* value = (const float*)d_in[2];
  const int*   eid   = (const int*)d_in[3];
  const float* ipw   = (const float*)d_in[4];
  const float* ipb   = (const float*)d_in[5];
  const float* opw   = (const float*)d_in[6];
  const float* opb   = (const float*)d_in[7];
  const float* ek    = (const float*)d_in[8];
  float* out = (float*)d_out;

  char* ws = (char*)d_ws;
  u16* Qs = (u16*)ws;              ws += (size_t)NHEAD * SEQ * HD * 2;
  u16* Kb = (u16*)ws;              ws += (size_t)NHEAD * SEQ * HD * 2;
  u16* Vb = (u16*)ws;              ws += (size_t)NHEAD * SEQ * HD * 2;     // transposed [h][d][j]
  unsigned* eidp = (unsigned*)ws;  ws += (size_t)SEQ * SEQ;                // u8-packed as u32
  float* Upart = (float*)ws;       ws += (size_t)JSPLIT * NHEAD * SEQ * HD * 4;
  float* mpart = (float*)ws;       ws += (size_t)JSPLIT * NHEAD * SEQ * 4;
  float* lpart = (float*)ws;       ws += (size_t)JSPLIT * NHEAD * SEQ * 4;

  fused_prep_gemm<<<dim3(QKV_BLOCKS + PACK_BLOCKS), dim3(256), 0, stream>>>(
      query, key_, value, ipw, ipb, eid, Qs, Kb, Vb, eidp);
  attn_kernel<<<dim3(SEQ / 64, NHEAD, JSPLIT), dim3(256), 0, stream>>>(
      Qs, Kb, Vb, eidp, ek, Upart, mpart, lpart);
  combine_outproj<<<dim3(EMB / 64, SEQ / 64), dim3(256), 0, stream>>>(
      Upart, mpart, lpart, opw, opb, out);
}

// Round 7
// 158.853 us; speedup vs baseline: 1.0400x; 1.0388x over previous
//
#include <hip/hip_runtime.h>
#include <hip/hip_bf16.h>

#define NHEAD 8
#define SEQ   2048
#define HD    64
#define EMB   512
#define NTYPE 10
#define JSPLIT 4

#define QKV_NT (3 * EMB / 64)          // 24 n-tiles
#define QKV_MT (SEQ / 64)              // 32 m-tiles
#define QKV_BLOCKS (QKV_NT * QKV_MT)   // 768
#define PACK_BLOCKS (SEQ * SEQ / 4 / 256)  // 4096

#define QSCALE 0.180336878f            // 0.125 * log2(e): exp2-domain softmax

typedef unsigned short u16;
typedef __attribute__((ext_vector_type(8))) short short8;
typedef __attribute__((ext_vector_type(4))) float float4v;

union F8 { short8 v; uint4 u4; u16 us[8]; };

__device__ __forceinline__ float bf2f(u16 u){
  union { unsigned u; float f; } w; w.u = ((unsigned)u) << 16; return w.f;
}
__device__ __forceinline__ u16 f2bf(float f){
  union { float f; unsigned u; } w; w.f = f;
  unsigned u = w.u;
  u += 0x7fffu + ((u >> 16) & 1u);   // RNE
  return (u16)(u >> 16);
}
// HW v_cvt_pk_bf16_f32 (RNE): lo -> low u16, hi -> high u16
__device__ __forceinline__ unsigned cvtpk(float lo, float hi){
  union { __hip_bfloat162 b; unsigned u; } w;
  w.b = __float22bfloat162_rn(float2{lo, hi});
  return w.u;
}
__device__ __forceinline__ uint4 pk8(float4 a, float4 b){
  uint4 p; p.x = cvtpk(a.x, a.y); p.y = cvtpk(a.z, a.w);
           p.z = cvtpk(b.x, b.y); p.w = cvtpk(b.z, b.w);
  return p;
}

// ---------------------------------------------------------------- K1: QKV projection (fp32 direct) + eid pack
// blocks [0,768): 64x64-tile GEMM, BK=64 (8 MFMA per barrier-pair), reg-staged fp32->bf16,
//                 register prefetch. Q scaled by QSCALE (exp2-domain).
// blocks [768, 768+4096): eid int32 -> u8 pack.
__global__ __launch_bounds__(256) void fused_prep_gemm(
    const float* __restrict__ q, const float* __restrict__ k, const float* __restrict__ v,
    const float* __restrict__ ipw, const float* __restrict__ ipb, const int* __restrict__ eid,
    u16* __restrict__ Qs, u16* __restrict__ Kb, u16* __restrict__ Vb,
    unsigned* __restrict__ eidp)
{
  const int b = blockIdx.x;
  const int t = threadIdx.x;

  if (b >= QKV_BLOCKS) {                       // ---- eid pack path
    const int i = (b - QKV_BLOCKS) * 256 + t;
    int4 vv = ((const int4*)eid)[i];
    eidp[i] = (unsigned)(vv.x & 0xff) | ((unsigned)(vv.y & 0xff) << 8) |
              ((unsigned)(vv.z & 0xff) << 16) | ((unsigned)(vv.w & 0xff) << 24);
    return;
  }

  __shared__ u16 As[64][72];
  __shared__ u16 Bs[64][72];

  const int nt = b % QKV_NT, mt = b / QKV_NT;
  const int n0 = nt * 64, m0 = mt * 64;
  const int z = n0 >> 9;                       // 0=q,1=k,2=v
  const float* A = (z == 0) ? q : (z == 1) ? k : v;
  const float scale = (z == 0) ? QSCALE : 1.0f;

  const int w = t >> 6, lane = t & 63, lr = lane & 15, lg = lane >> 4;
  const int wm = w >> 1, wn = w & 1;
  const int srow = t >> 2, kb16 = (t & 3) * 16;

  float4v acc[2][2];
#pragma unroll
  for (int mi = 0; mi < 2; mi++)
#pragma unroll
    for (int ni = 0; ni < 2; ni++) acc[mi][ni] = (float4v){0.f, 0.f, 0.f, 0.f};

  const float* pa = A   + (size_t)(m0 + srow) * EMB + kb16;
  const float* pw = ipw + (size_t)(n0 + srow) * EMB + kb16;

  float4 a[4], bb[4];
#pragma unroll
  for (int j = 0; j < 4; j++) { a[j] = *(const float4*)(pa + j * 4); bb[j] = *(const float4*)(pw + j * 4); }

  for (int k0 = 0; k0 < EMB; k0 += 64) {
    *(uint4*)&As[srow][kb16]     = pk8(a[0], a[1]);
    *(uint4*)&As[srow][kb16 + 8] = pk8(a[2], a[3]);
    *(uint4*)&Bs[srow][kb16]     = pk8(bb[0], bb[1]);
    *(uint4*)&Bs[srow][kb16 + 8] = pk8(bb[2], bb[3]);
    __syncthreads();
    if (k0 + 64 < EMB) {                       // prefetch next K-tile (hides under MFMA)
#pragma unroll
      for (int j = 0; j < 4; j++) {
        a[j]  = *(const float4*)(pa + k0 + 64 + j * 4);
        bb[j] = *(const float4*)(pw + k0 + 64 + j * 4);
      }
    }
    F8 af[2][2], bf_[2][2];
#pragma unroll
    for (int kc = 0; kc < 2; kc++) {
#pragma unroll
      for (int mi = 0; mi < 2; mi++)
        af[mi][kc].u4 = *(const uint4*)&As[wm * 32 + mi * 16 + lr][kc * 32 + lg * 8];
#pragma unroll
      for (int ni = 0; ni < 2; ni++)
        bf_[ni][kc].u4 = *(const uint4*)&Bs[wn * 32 + ni * 16 + lr][kc * 32 + lg * 8];
    }
#pragma unroll
    for (int kc = 0; kc < 2; kc++)
#pragma unroll
      for (int mi = 0; mi < 2; mi++)
#pragma unroll
        for (int ni = 0; ni < 2; ni++)
          acc[mi][ni] = __builtin_amdgcn_mfma_f32_16x16x32_bf16(af[mi][kc].v, bf_[ni][kc].v, acc[mi][ni], 0, 0, 0);
    __syncthreads();
  }

  u16* O = (z == 0) ? Qs : ((z == 1) ? Kb : Vb);
#pragma unroll
  for (int mi = 0; mi < 2; mi++) {
#pragma unroll
    for (int ni = 0; ni < 2; ni++) {
      const int n = n0 + wn * 32 + ni * 16 + lr;
      const int e = n & 511, h = e >> 6, d = e & 63;
      const float bias = ipb[n];
      const int mb = m0 + wm * 32 + mi * 16 + lg * 4;
      if (z < 2) {
#pragma unroll
        for (int r = 0; r < 4; r++)
          O[((size_t)h * SEQ + mb + r) * HD + d] = f2bf((acc[mi][ni][r] + bias) * scale);
      } else {
        ushort4 pk;
        pk.x = f2bf(acc[mi][ni][0] + bias); pk.y = f2bf(acc[mi][ni][1] + bias);
        pk.z = f2bf(acc[mi][ni][2] + bias); pk.w = f2bf(acc[mi][ni][3] + bias);
        *(ushort4*)(O + ((size_t)(h * HD + d)) * SEQ + mb) = pk;   // V^T layout [h][d][m]
      }
    }
  }
}

// ---------------------------------------------------------------- K2: flash attention with edge bias
// Swapped QK^T: S^T = mfma(K, Q) -> lane (lr,lg) owns row i=wave*16+lr,
// scores j = c*16+lg*4+r. Softmax m/l in REGISTERS; exp2-domain; eid gathered from
// global per-lane-row; P packed via v_cvt_pk_bf16_f32. T14 reg-prefetch of K/V/eid.
// Partials written in BF16 (packed cvt_pk).
// grid: x = 32 i-tiles, y = 8 heads, z = JSPLIT j-chunks. Vb TRANSPOSED [h][d][j].
__global__ __launch_bounds__(256) void attn_kernel(
    const u16* __restrict__ Qs, const u16* __restrict__ Kb, const u16* __restrict__ Vb,
    const unsigned* __restrict__ eid32, const float* __restrict__ EK,
    u16* __restrict__ Upart, float* __restrict__ mpart, float* __restrict__ lpart)
{
  __shared__ u16 Kt[64][72];            // K tile [j][d]
  __shared__ u16 Vt[64][72];            // V tile transposed [d][j]
  __shared__ u16 Pl[4][16][72];         // per-wave P [i_local][j_local]
  __shared__ float tsl[64][13];         // type scores per row (+pad)
  __shared__ float ekl[NTYPE][64];

  const int t = threadIdx.x;
  const int wave = t >> 6, lane = t & 63, lr = lane & 15, lg = lane >> 4;
  const int i0 = blockIdx.x * 64;
  const int h  = blockIdx.y;
  const int z  = blockIdx.z;

  for (int i = t; i < NTYPE * 64; i += 256) ekl[i >> 6][i & 63] = EK[i];
  __syncthreads();

  // type scores ts[row][type] = q_scaled[row] . EK[type]  (exp2-domain via Q scale)
  {
    const int row = t >> 2, tt = t & 3;
    const u16* qr = Qs + ((size_t)h * SEQ + i0 + row) * HD;
    float a0 = 0.f, a1 = 0.f, a2 = 0.f;
    for (int d0 = 0; d0 < HD; d0 += 8) {
      uint4 qq = *(const uint4*)(qr + d0);
      const u16* qu = (const u16*)&qq;
#pragma unroll
      for (int e = 0; e < 8; e++) {
        float qf = bf2f(qu[e]);
        a0 += qf * ekl[tt][d0 + e];
        a1 += qf * ekl[tt + 4][d0 + e];
        a2 += qf * ekl[(tt < 2) ? (tt + 8) : 8][d0 + e];
      }
    }
    tsl[row][tt] = a0; tsl[row][tt + 4] = a1;
    if (tt < 2) tsl[row][tt + 8] = a2;
  }

  // Q fragments (B operand), held in regs all iterations
  F8 qf[2];
#pragma unroll
  for (int kc = 0; kc < 2; kc++)
    qf[kc].u4 = *(const uint4*)(Qs + ((size_t)h * SEQ + i0 + wave * 16 + lr) * HD + kc * 32 + lg * 8);

  float4v ao[4];
#pragma unroll
  for (int d = 0; d < 4; d++) ao[d] = (float4v){0.f, 0.f, 0.f, 0.f};
  float m_i = -1e30f, l_i = 0.f;       // own-row softmax state (dup x4 across lg)

  const int srow = t >> 2, sdc = (t & 3) * 16;
  const int jbase = z * (SEQ / JSPLIT);
  const int NT = (SEQ / JSPLIT) / 64;
  const unsigned* erow = eid32 + (size_t)(i0 + wave * 16 + lr) * (SEQ / 4);

  uint4 kp0, kp1, vp0, vp1;
  unsigned ed[4], edn[4];
  {
    const u16* kp = Kb + ((size_t)h * SEQ + jbase + srow) * HD + sdc;
    kp0 = *(const uint4*)kp; kp1 = *(const uint4*)(kp + 8);
    const u16* vp = Vb + ((size_t)(h * HD + srow)) * SEQ + jbase + sdc;
    vp0 = *(const uint4*)vp; vp1 = *(const uint4*)(vp + 8);
    *(uint4*)&Kt[srow][sdc] = kp0; *(uint4*)&Kt[srow][sdc + 8] = kp1;
    *(uint4*)&Vt[srow][sdc] = vp0; *(uint4*)&Vt[srow][sdc + 8] = vp1;
    const int ej = jbase >> 2;
#pragma unroll
    for (int c = 0; c < 4; c++) ed[c] = erow[ej + c * 4 + lg];
  }

  for (int jt = 0; jt < NT; jt++) {
    __syncthreads();                               // tile jt staged (and tsl on jt==0)

    if (jt + 1 < NT) {                             // T14: issue next tile's loads
      const int jn = jbase + (jt + 1) * 64;
      const u16* kp = Kb + ((size_t)h * SEQ + jn + srow) * HD + sdc;
      kp0 = *(const uint4*)kp; kp1 = *(const uint4*)(kp + 8);
      const u16* vp = Vb + ((size_t)(h * HD + srow)) * SEQ + jn + sdc;
      vp0 = *(const uint4*)vp; vp1 = *(const uint4*)(vp + 8);
      const int ejn = jn >> 2;
#pragma unroll
      for (int c = 0; c < 4; c++) edn[c] = erow[ejn + c * 4 + lg];
    }

    // ---- S^T = mfma(K, Q): sacc[c][r] = S[i=wave*16+lr][j=c*16+lg*4+r]
    float4v sacc[4];
#pragma unroll
    for (int c = 0; c < 4; c++) sacc[c] = (float4v){0.f, 0.f, 0.f, 0.f};
#pragma unroll
    for (int kc = 0; kc < 2; kc++) {
#pragma unroll
      for (int c = 0; c < 4; c++) {
        F8 kf; kf.u4 = *(const uint4*)&Kt[c * 16 + lr][kc * 32 + lg * 8];
        sacc[c] = __builtin_amdgcn_mfma_f32_16x16x32_bf16(kf.v, qf[kc].v, sacc[c], 0, 0, 0);
      }
    }

    // ---- edge bias (byte r of ed[c] = type of score sacc[c][r]) + row max
    float rmax = -1e30f;
#pragma unroll
    for (int c = 0; c < 4; c++) {
      const unsigned e = ed[c];
#pragma unroll
      for (int r = 0; r < 4; r++) {
        const float s = sacc[c][r] + tsl[wave * 16 + lr][(e >> (r * 8)) & 0xffu];
        sacc[c][r] = s;
        rmax = fmaxf(rmax, s);
      }
    }
    rmax = fmaxf(rmax, __shfl_xor(rmax, 16));
    rmax = fmaxf(rmax, __shfl_xor(rmax, 32));
    const float mnew = fmaxf(m_i, rmax);
    const float fct = exp2f(m_i - mnew);
    float rsum = 0.f;
#pragma unroll
    for (int c = 0; c < 4; c++) {
#pragma unroll
      for (int r = 0; r < 4; r++) {
        const float p = exp2f(sacc[c][r] - mnew);
        sacc[c][r] = p;
        rsum += p;
      }
    }
    rsum += __shfl_xor(rsum, 16);
    rsum += __shfl_xor(rsum, 32);
    l_i = l_i * fct + rsum;
    m_i = mnew;

    // ---- pack P (HW cvt_pk RNE), 8B write per c
#pragma unroll
    for (int c = 0; c < 4; c++) {
      uint2 pw;
      pw.x = cvtpk(sacc[c][0], sacc[c][1]);
      pw.y = cvtpk(sacc[c][2], sacc[c][3]);
      *(uint2*)&Pl[wave][lr][c * 16 + lg * 4] = pw;
    }
    // rescale O (fct is own-row)
#pragma unroll
    for (int db = 0; db < 4; db++) {
#pragma unroll
      for (int r = 0; r < 4; r++) ao[db][r] *= fct;
    }
    // ---- O^T += V^T P^T   (D: row=d_local, col=i_local=lr)
#pragma unroll
    for (int kc = 0; kc < 2; kc++) {
      F8 pf; pf.u4 = *(const uint4*)&Pl[wave][lr][kc * 32 + lg * 8];
#pragma unroll
      for (int db = 0; db < 4; db++) {
        F8 vf; vf.u4 = *(const uint4*)&Vt[db * 16 + lr][kc * 32 + lg * 8];
        ao[db] = __builtin_amdgcn_mfma_f32_16x16x32_bf16(vf.v, pf.v, ao[db], 0, 0, 0);
      }
    }

    __syncthreads();                               // all waves done reading tile jt
    if (jt + 1 < NT) {                             // T14: write prefetched tile
      *(uint4*)&Kt[srow][sdc] = kp0; *(uint4*)&Kt[srow][sdc + 8] = kp1;
      *(uint4*)&Vt[srow][sdc] = vp0; *(uint4*)&Vt[srow][sdc + 8] = vp1;
#pragma unroll
      for (int c = 0; c < 4; c++) ed[c] = edn[c];
    }
  }

  // ---- write partials (unnormalized U in BF16, m/l fp32, base-2 domain)
  {
    const size_t base = (((size_t)z * NHEAD + h) * SEQ + i0) * HD;
    const int n = wave * 16 + lr;
#pragma unroll
    for (int db = 0; db < 4; db++) {
      uint2 pw;
      pw.x = cvtpk(ao[db][0], ao[db][1]);
      pw.y = cvtpk(ao[db][2], ao[db][3]);
      *(uint2*)(Upart + base + (size_t)n * HD + db * 16 + lg * 4) = pw;
    }
    if (lg == 0) {
      mpart[((size_t)z * NHEAD + h) * SEQ + i0 + n] = m_i;
      lpart[((size_t)z * NHEAD + h) * SEQ + i0 + n] = l_i;
    }
  }
}

// ---------------------------------------------------------------- K3: combine + out-projection
// 64x64-tile GEMM (BK=64) out = AO * opw^T + opb; AO combined on the fly from JSPLIT
// bf16 partials (weights w_z/Ls precomputed per (h,row) in LDS, exp2-domain).
__global__ __launch_bounds__(256) void combine_outproj(
    const u16* __restrict__ Upart, const float* __restrict__ mpart,
    const float* __restrict__ lpart, const float* __restrict__ opw,
    const float* __restrict__ opb, float* __restrict__ out)
{
  __shared__ u16 As[64][72];
  __shared__ u16 Bs[64][72];
  __shared__ float cww[JSPLIT][NHEAD][64];

  const int t = threadIdx.x;
  const int n0 = blockIdx.x * 64;   // output col tile
  const int m0 = blockIdx.y * 64;   // row tile

  for (int idx = t; idx < NHEAD * 64; idx += 256) {
    const int hh = idx >> 6, nl = idx & 63;
    const int gn = m0 + nl;
    float mz[JSPLIT], wz[JSPLIT];
    float M = -1e30f;
#pragma unroll
    for (int zz = 0; zz < JSPLIT; zz++) {
      mz[zz] = mpart[((size_t)zz * NHEAD + hh) * SEQ + gn];
      M = fmaxf(M, mz[zz]);
    }
    float Ls = 0.f;
#pragma unroll
    for (int zz = 0; zz < JSPLIT; zz++) {
      wz[zz] = exp2f(mz[zz] - M);
      Ls += wz[zz] * lpart[((size_t)zz * NHEAD + hh) * SEQ + gn];
    }
    const float inv = 1.0f / Ls;
#pragma unroll
    for (int zz = 0; zz < JSPLIT; zz++) cww[zz][hh][nl] = wz[zz] * inv;
  }
  __syncthreads();

  const int w = t >> 6, lane = t & 63, lr = lane & 15, lg = lane >> 4;
  const int wm = w >> 1, wn = w & 1;
  const int srow = t >> 2, kb16 = (t & 3) * 16;

  float4v acc[2][2];
#pragma unroll
  for (int mi = 0; mi < 2; mi++)
#pragma unroll
    for (int ni = 0; ni < 2; ni++) acc[mi][ni] = (float4v){0.f, 0.f, 0.f, 0.f};

  const float* pw = opw + (size_t)(n0 + srow) * EMB + kb16;

  int hcur = kb16 >> 6, dcur = kb16 & 63;
  uint4 ua[JSPLIT][2];
#pragma unroll
  for (int zz = 0; zz < JSPLIT; zz++) {
    const u16* pu = Upart + (((size_t)zz * NHEAD + hcur) * SEQ + m0 + srow) * HD + dcur;
    ua[zz][0] = *(const uint4*)pu; ua[zz][1] = *(const uint4*)(pu + 8);
  }
  float4 bb[4];
#pragma unroll
  for (int j = 0; j < 4; j++) bb[j] = *(const float4*)(pw + j * 4);

  for (int k0 = 0; k0 < EMB; k0 += 64) {
    // combine -> bf16 A tile (16 elems per thread)
    {
      float cc[16];
#pragma unroll
      for (int j = 0; j < 16; j++) cc[j] = 0.f;
#pragma unroll
      for (int zz = 0; zz < JSPLIT; zz++) {
        const float wgt = cww[zz][hcur][srow];
        F8 q0, q1; q0.u4 = ua[zz][0]; q1.u4 = ua[zz][1];
#pragma unroll
        for (int j = 0; j < 8; j++) {
          cc[j]     += wgt * bf2f((u16)q0.us[j]);
          cc[j + 8] += wgt * bf2f((u16)q1.us[j]);
        }
      }
      float4 c0 = {cc[0], cc[1], cc[2], cc[3]},   c1 = {cc[4], cc[5], cc[6], cc[7]};
      float4 c2 = {cc[8], cc[9], cc[10], cc[11]}, c3 = {cc[12], cc[13], cc[14], cc[15]};
      *(uint4*)&As[srow][kb16]     = pk8(c0, c1);
      *(uint4*)&As[srow][kb16 + 8] = pk8(c2, c3);
      *(uint4*)&Bs[srow][kb16]     = pk8(bb[0], bb[1]);
      *(uint4*)&Bs[srow][kb16 + 8] = pk8(bb[2], bb[3]);
    }
    __syncthreads();
    if (k0 + 64 < EMB) {
      const int e = k0 + 64 + kb16;
      hcur = e >> 6; dcur = e & 63;
#pragma unroll
      for (int zz = 0; zz < JSPLIT; zz++) {
        const u16* pu = Upart + (((size_t)zz * NHEAD + hcur) * SEQ + m0 + srow) * HD + dcur;
        ua[zz][0] = *(const uint4*)pu; ua[zz][1] = *(const uint4*)(pu + 8);
      }
#pragma unroll
      for (int j = 0; j < 4; j++) bb[j] = *(const float4*)(pw + k0 + 64 + j * 4);
    }
    F8 af[2][2], bf_[2][2];
#pragma unroll
    for (int kc = 0; kc < 2; kc++) {
#pragma unroll
      for (int mi = 0; mi < 2; mi++)
        af[mi][kc].u4 = *(const uint4*)&As[wm * 32 + mi * 16 + lr][kc * 32 + lg * 8];
#pragma unroll
      for (int ni = 0; ni < 2; ni++)
        bf_[ni][kc].u4 = *(const uint4*)&Bs[wn * 32 + ni * 16 + lr][kc * 32 + lg * 8];
    }
#pragma unroll
    for (int kc = 0; kc < 2; kc++)
#pragma unroll
      for (int mi = 0; mi < 2; mi++)
#pragma unroll
        for (int ni = 0; ni < 2; ni++)
          acc[mi][ni] = __builtin_amdgcn_mfma_f32_16x16x32_bf16(af[mi][kc].v, bf_[ni][kc].v, acc[mi][ni], 0, 0, 0);
    __syncthreads();
  }

#pragma unroll
  for (int mi = 0; mi < 2; mi++) {
#pragma unroll
    for (int ni = 0; ni < 2; ni++) {
      const int n = n0 + wn * 32 + ni * 16 + lr;
      const float bias = opb[n];
      const int mb = m0 + wm * 32 + mi * 16 + lg * 4;
#pragma unroll
      for (int r = 0; r < 4; r++)
        out[(size_t)(mb + r) * EMB + n] = acc[mi][ni][r] + bias;
    }
  }
}

// ---------------------------------------------------------------- launcher
extern "C" void kernel_launch(void* const* d_in, const int* in_sizes, int n_in,
                              void* d_out, int out_size, void* d_ws, size_t ws_size,
                              hipStream_t stream)
{
  const float* query = (const float*)d_in[0];
  const float* key_  = (const float*)d_in[1];
  const float* value = (const float*)d_in[2];
  const int*   eid   = (const int*)d_in[3];
  const float* ipw   = (const float*)d_in[4];
  const float* ipb   = (const float*)d_in[5];
  const float* opw   = (const float*)d_in[6];
  const float* opb   = (const float*)d_in[7];
  const float* ek    = (const float*)d_in[8];
  float* out = (float*)d_out;

  char* ws = (char*)d_ws;
  u16* Qs = (u16*)ws;              ws += (size_t)NHEAD * SEQ * HD * 2;
  u16* Kb = (u16*)ws;              ws += (size_t)NHEAD * SEQ * HD * 2;
  u16* Vb = (u16*)ws;              ws += (size_t)NHEAD * SEQ * HD * 2;     // transposed [h][d][j]
  unsigned* eidp = (unsigned*)ws;  ws += (size_t)SEQ * SEQ;                // u8-packed as u32
  u16* Upart = (u16*)ws;           ws += (size_t)JSPLIT * NHEAD * SEQ * HD * 2;  // bf16 partials
  float* mpart = (float*)ws;       ws += (size_t)JSPLIT * NHEAD * SEQ * 4;
  float* lpart = (float*)ws;       ws += (size_t)JSPLIT * NHEAD * SEQ * 4;

  fused_prep_gemm<<<dim3(QKV_BLOCKS + PACK_BLOCKS), dim3(256), 0, stream>>>(
      query, key_, value, ipw, ipb, eid, Qs, Kb, Vb, eidp);
  attn_kernel<<<dim3(SEQ / 64, NHEAD, JSPLIT), dim3(256), 0, stream>>>(
      Qs, Kb, Vb, eidp, ek, Upart, mpart, lpart);
  combine_outproj<<<dim3(EMB / 64, SEQ / 64), dim3(256), 0, stream>>>(
      Upart, mpart, lpart, opw, opb, out);
}

// Round 8
// 149.968 us; speedup vs baseline: 1.1016x; 1.0592x over previous
//
#include <hip/hip_runtime.h>
#include <hip/hip_bf16.h>

#define NHEAD 8
#define SEQ   2048
#define HD    64
#define EMB   512
#define NTYPE 10
#define JSPLIT 4

#define QKV_NT (3 * EMB / 64)          // 24 n-tiles
#define QKV_MT (SEQ / 64)              // 32 m-tiles
#define QKV_BLOCKS (QKV_NT * QKV_MT)   // 768
#define PACK_BLOCKS (SEQ * SEQ / 4 / 256)  // 4096

#define QSCALE 0.180336878f            // 0.125 * log2(e): exp2-domain softmax

typedef unsigned short u16;
typedef __attribute__((ext_vector_type(8))) short short8;
typedef __attribute__((ext_vector_type(4))) float float4v;

union F8 { short8 v; uint4 u4; u16 us[8]; };

__device__ __forceinline__ float bf2f(u16 u){
  union { unsigned u; float f; } w; w.u = ((unsigned)u) << 16; return w.f;
}
__device__ __forceinline__ u16 f2bf(float f){
  union { float f; unsigned u; } w; w.f = f;
  unsigned u = w.u;
  u += 0x7fffu + ((u >> 16) & 1u);   // RNE
  return (u16)(u >> 16);
}
// HW v_cvt_pk_bf16_f32 (RNE)
__device__ __forceinline__ unsigned cvtpk(float lo, float hi){
  union { __hip_bfloat162 b; unsigned u; } w;
  w.b = __float22bfloat162_rn(float2{lo, hi});
  return w.u;
}
__device__ __forceinline__ uint4 pk8(float4 a, float4 b){
  uint4 p; p.x = cvtpk(a.x, a.y); p.y = cvtpk(a.z, a.w);
           p.z = cvtpk(b.x, b.y); p.w = cvtpk(b.z, b.w);
  return p;
}

// ---------------------------------------------------------------- K1: QKV projection (fp32 direct) + eid pack
// GEMM blocks [0,768): 64x64-tile, BK=64, reg-staged fp32->bf16, register prefetch.
// T1 XCD grouping: hw xcd = dispatch%8; XCD X owns m-tiles [4X,4X+4) x all 24 n
//   -> per-XCD working set (A-rows 1.5MB + W 3MB) ~ L2-resident.
// blocks [768, 768+4096): eid int32 -> u8 pack.
__global__ __launch_bounds__(256) void fused_prep_gemm(
    const float* __restrict__ q, const float* __restrict__ k, const float* __restrict__ v,
    const float* __restrict__ ipw, const float* __restrict__ ipb, const int* __restrict__ eid,
    u16* __restrict__ Qs, u16* __restrict__ Kb, u16* __restrict__ Vb,
    unsigned* __restrict__ eidp)
{
  const int b = blockIdx.x;
  const int t = threadIdx.x;

  if (b >= QKV_BLOCKS) {                       // ---- eid pack path
    const int i = (b - QKV_BLOCKS) * 256 + t;
    int4 vv = ((const int4*)eid)[i];
    eidp[i] = (unsigned)(vv.x & 0xff) | ((unsigned)(vv.y & 0xff) << 8) |
              ((unsigned)(vv.z & 0xff) << 16) | ((unsigned)(vv.w & 0xff) << 24);
    return;
  }

  __shared__ u16 As[64][72];
  __shared__ u16 Bs[64][72];

  // XCD-grouped tile map (bijective): X = b%8, j = b/8; mt = 4X + (j&3), nt = j>>2
  const int X = b & 7, jb = b >> 3;
  const int mt = X * 4 + (jb & 3), nt = jb >> 2;
  const int n0 = nt * 64, m0 = mt * 64;
  const int z = n0 >> 9;                       // 0=q,1=k,2=v
  const float* A = (z == 0) ? q : (z == 1) ? k : v;
  const float scale = (z == 0) ? QSCALE : 1.0f;

  const int w = t >> 6, lane = t & 63, lr = lane & 15, lg = lane >> 4;
  const int wm = w >> 1, wn = w & 1;
  const int srow = t >> 2, kb16 = (t & 3) * 16;

  float4v acc[2][2];
#pragma unroll
  for (int mi = 0; mi < 2; mi++)
#pragma unroll
    for (int ni = 0; ni < 2; ni++) acc[mi][ni] = (float4v){0.f, 0.f, 0.f, 0.f};

  const float* pa = A   + (size_t)(m0 + srow) * EMB + kb16;
  const float* pw = ipw + (size_t)(n0 + srow) * EMB + kb16;

  float4 a[4], bb[4];
#pragma unroll
  for (int j = 0; j < 4; j++) { a[j] = *(const float4*)(pa + j * 4); bb[j] = *(const float4*)(pw + j * 4); }

  for (int k0 = 0; k0 < EMB; k0 += 64) {
    *(uint4*)&As[srow][kb16]     = pk8(a[0], a[1]);
    *(uint4*)&As[srow][kb16 + 8] = pk8(a[2], a[3]);
    *(uint4*)&Bs[srow][kb16]     = pk8(bb[0], bb[1]);
    *(uint4*)&Bs[srow][kb16 + 8] = pk8(bb[2], bb[3]);
    __syncthreads();
    if (k0 + 64 < EMB) {                       // prefetch next K-tile
#pragma unroll
      for (int j = 0; j < 4; j++) {
        a[j]  = *(const float4*)(pa + k0 + 64 + j * 4);
        bb[j] = *(const float4*)(pw + k0 + 64 + j * 4);
      }
    }
    F8 af[2][2], bf_[2][2];
#pragma unroll
    for (int kc = 0; kc < 2; kc++) {
#pragma unroll
      for (int mi = 0; mi < 2; mi++)
        af[mi][kc].u4 = *(const uint4*)&As[wm * 32 + mi * 16 + lr][kc * 32 + lg * 8];
#pragma unroll
      for (int ni = 0; ni < 2; ni++)
        bf_[ni][kc].u4 = *(const uint4*)&Bs[wn * 32 + ni * 16 + lr][kc * 32 + lg * 8];
    }
#pragma unroll
    for (int kc = 0; kc < 2; kc++)
#pragma unroll
      for (int mi = 0; mi < 2; mi++)
#pragma unroll
        for (int ni = 0; ni < 2; ni++)
          acc[mi][ni] = __builtin_amdgcn_mfma_f32_16x16x32_bf16(af[mi][kc].v, bf_[ni][kc].v, acc[mi][ni], 0, 0, 0);
    __syncthreads();
  }

  u16* O = (z == 0) ? Qs : ((z == 1) ? Kb : Vb);
#pragma unroll
  for (int mi = 0; mi < 2; mi++) {
#pragma unroll
    for (int ni = 0; ni < 2; ni++) {
      const int n = n0 + wn * 32 + ni * 16 + lr;
      const int e = n & 511, h = e >> 6, d = e & 63;
      const float bias = ipb[n];
      const int mb = m0 + wm * 32 + mi * 16 + lg * 4;
      if (z < 2) {
#pragma unroll
        for (int r = 0; r < 4; r++)
          O[((size_t)h * SEQ + mb + r) * HD + d] = f2bf((acc[mi][ni][r] + bias) * scale);
      } else {
        ushort4 pk;
        pk.x = f2bf(acc[mi][ni][0] + bias); pk.y = f2bf(acc[mi][ni][1] + bias);
        pk.z = f2bf(acc[mi][ni][2] + bias); pk.w = f2bf(acc[mi][ni][3] + bias);
        *(ushort4*)(O + ((size_t)(h * HD + d)) * SEQ + mb) = pk;   // V^T layout [h][d][m]
      }
    }
  }
}

// ---------------------------------------------------------------- K2: flash attention with edge bias
// Swapped QK^T (lane owns a Q-row), softmax m/l in regs, exp2-domain, global eid gather,
// cvt_pk P-pack, T14 reg-prefetch, bf16 partials.
// Flattened 1024-block grid with T1 XCD grouping: XCD X owns 4 (h,z) pairs
//   -> per-XCD K/V working set 512KB L2-resident. Vb TRANSPOSED [h][d][j].
__global__ __launch_bounds__(256) void attn_kernel(
    const u16* __restrict__ Qs, const u16* __restrict__ Kb, const u16* __restrict__ Vb,
    const unsigned* __restrict__ eid32, const float* __restrict__ EK,
    u16* __restrict__ Upart, float* __restrict__ mpart, float* __restrict__ lpart)
{
  __shared__ u16 Kt[64][72];            // K tile [j][d]
  __shared__ u16 Vt[64][72];            // V tile transposed [d][j]
  __shared__ u16 Pl[4][16][72];         // per-wave P [i_local][j_local]
  __shared__ float tsl[64][13];         // type scores per row (+pad)
  __shared__ float ekl[NTYPE][64];

  const int t = threadIdx.x;
  const int wave = t >> 6, lane = t & 63, lr = lane & 15, lg = lane >> 4;
  // XCD-grouped (bijective): X = b%8, j = b/8; pair p = 4X + (j>>5); x = j&31
  const int bb_ = blockIdx.x;
  const int X = bb_ & 7, jj = bb_ >> 3;
  const int p = X * 4 + (jj >> 5);
  const int i0 = (jj & 31) * 64;
  const int h  = p >> 2;
  const int z  = p & 3;

  for (int i = t; i < NTYPE * 64; i += 256) ekl[i >> 6][i & 63] = EK[i];
  __syncthreads();

  // type scores ts[row][type] = q_scaled[row] . EK[type]  (exp2-domain via Q scale)
  {
    const int row = t >> 2, tt = t & 3;
    const u16* qr = Qs + ((size_t)h * SEQ + i0 + row) * HD;
    float a0 = 0.f, a1 = 0.f, a2 = 0.f;
    for (int d0 = 0; d0 < HD; d0 += 8) {
      uint4 qq = *(const uint4*)(qr + d0);
      const u16* qu = (const u16*)&qq;
#pragma unroll
      for (int e = 0; e < 8; e++) {
        float qf = bf2f(qu[e]);
        a0 += qf * ekl[tt][d0 + e];
        a1 += qf * ekl[tt + 4][d0 + e];
        a2 += qf * ekl[(tt < 2) ? (tt + 8) : 8][d0 + e];
      }
    }
    tsl[row][tt] = a0; tsl[row][tt + 4] = a1;
    if (tt < 2) tsl[row][tt + 8] = a2;
  }

  // Q fragments (B operand), held in regs all iterations
  F8 qf[2];
#pragma unroll
  for (int kc = 0; kc < 2; kc++)
    qf[kc].u4 = *(const uint4*)(Qs + ((size_t)h * SEQ + i0 + wave * 16 + lr) * HD + kc * 32 + lg * 8);

  float4v ao[4];
#pragma unroll
  for (int d = 0; d < 4; d++) ao[d] = (float4v){0.f, 0.f, 0.f, 0.f};
  float m_i = -1e30f, l_i = 0.f;       // own-row softmax state (dup x4 across lg)

  const int srow = t >> 2, sdc = (t & 3) * 16;
  const int jbase = z * (SEQ / JSPLIT);
  const int NT = (SEQ / JSPLIT) / 64;
  const unsigned* erow = eid32 + (size_t)(i0 + wave * 16 + lr) * (SEQ / 4);

  uint4 kp0, kp1, vp0, vp1;
  unsigned ed[4], edn[4];
  {
    const u16* kp = Kb + ((size_t)h * SEQ + jbase + srow) * HD + sdc;
    kp0 = *(const uint4*)kp; kp1 = *(const uint4*)(kp + 8);
    const u16* vp = Vb + ((size_t)(h * HD + srow)) * SEQ + jbase + sdc;
    vp0 = *(const uint4*)vp; vp1 = *(const uint4*)(vp + 8);
    *(uint4*)&Kt[srow][sdc] = kp0; *(uint4*)&Kt[srow][sdc + 8] = kp1;
    *(uint4*)&Vt[srow][sdc] = vp0; *(uint4*)&Vt[srow][sdc + 8] = vp1;
    const int ej = jbase >> 2;
#pragma unroll
    for (int c = 0; c < 4; c++) ed[c] = erow[ej + c * 4 + lg];
  }

  for (int jt = 0; jt < NT; jt++) {
    __syncthreads();                               // tile jt staged (and tsl on jt==0)

    if (jt + 1 < NT) {                             // T14: issue next tile's loads
      const int jn = jbase + (jt + 1) * 64;
      const u16* kp = Kb + ((size_t)h * SEQ + jn + srow) * HD + sdc;
      kp0 = *(const uint4*)kp; kp1 = *(const uint4*)(kp + 8);
      const u16* vp = Vb + ((size_t)(h * HD + srow)) * SEQ + jn + sdc;
      vp0 = *(const uint4*)vp; vp1 = *(const uint4*)(vp + 8);
      const int ejn = jn >> 2;
#pragma unroll
      for (int c = 0; c < 4; c++) edn[c] = erow[ejn + c * 4 + lg];
    }

    // ---- S^T = mfma(K, Q): sacc[c][r] = S[i=wave*16+lr][j=c*16+lg*4+r]
    float4v sacc[4];
#pragma unroll
    for (int c = 0; c < 4; c++) sacc[c] = (float4v){0.f, 0.f, 0.f, 0.f};
#pragma unroll
    for (int kc = 0; kc < 2; kc++) {
#pragma unroll
      for (int c = 0; c < 4; c++) {
        F8 kf; kf.u4 = *(const uint4*)&Kt[c * 16 + lr][kc * 32 + lg * 8];
        sacc[c] = __builtin_amdgcn_mfma_f32_16x16x32_bf16(kf.v, qf[kc].v, sacc[c], 0, 0, 0);
      }
    }

    // ---- edge bias (byte r of ed[c] = type of score sacc[c][r]) + row max
    float rmax = -1e30f;
#pragma unroll
    for (int c = 0; c < 4; c++) {
      const unsigned e = ed[c];
#pragma unroll
      for (int r = 0; r < 4; r++) {
        const float s = sacc[c][r] + tsl[wave * 16 + lr][(e >> (r * 8)) & 0xffu];
        sacc[c][r] = s;
        rmax = fmaxf(rmax, s);
      }
    }
    rmax = fmaxf(rmax, __shfl_xor(rmax, 16));
    rmax = fmaxf(rmax, __shfl_xor(rmax, 32));
    const float mnew = fmaxf(m_i, rmax);
    const float fct = exp2f(m_i - mnew);
    float rsum = 0.f;
#pragma unroll
    for (int c = 0; c < 4; c++) {
#pragma unroll
      for (int r = 0; r < 4; r++) {
        const float p_ = exp2f(sacc[c][r] - mnew);
        sacc[c][r] = p_;
        rsum += p_;
      }
    }
    rsum += __shfl_xor(rsum, 16);
    rsum += __shfl_xor(rsum, 32);
    l_i = l_i * fct + rsum;
    m_i = mnew;

    // ---- pack P (HW cvt_pk RNE), 8B write per c
#pragma unroll
    for (int c = 0; c < 4; c++) {
      uint2 pw;
      pw.x = cvtpk(sacc[c][0], sacc[c][1]);
      pw.y = cvtpk(sacc[c][2], sacc[c][3]);
      *(uint2*)&Pl[wave][lr][c * 16 + lg * 4] = pw;
    }
    // rescale O (fct is own-row)
#pragma unroll
    for (int db = 0; db < 4; db++) {
#pragma unroll
      for (int r = 0; r < 4; r++) ao[db][r] *= fct;
    }
    // ---- O^T += V^T P^T   (D: row=d_local, col=i_local=lr)
#pragma unroll
    for (int kc = 0; kc < 2; kc++) {
      F8 pf; pf.u4 = *(const uint4*)&Pl[wave][lr][kc * 32 + lg * 8];
#pragma unroll
      for (int db = 0; db < 4; db++) {
        F8 vf; vf.u4 = *(const uint4*)&Vt[db * 16 + lr][kc * 32 + lg * 8];
        ao[db] = __builtin_amdgcn_mfma_f32_16x16x32_bf16(vf.v, pf.v, ao[db], 0, 0, 0);
      }
    }

    __syncthreads();                               // all waves done reading tile jt
    if (jt + 1 < NT) {                             // T14: write prefetched tile
      *(uint4*)&Kt[srow][sdc] = kp0; *(uint4*)&Kt[srow][sdc + 8] = kp1;
      *(uint4*)&Vt[srow][sdc] = vp0; *(uint4*)&Vt[srow][sdc + 8] = vp1;
#pragma unroll
      for (int c = 0; c < 4; c++) ed[c] = edn[c];
    }
  }

  // ---- write partials (unnormalized U in BF16, m/l fp32, base-2 domain)
  {
    const size_t base = (((size_t)z * NHEAD + h) * SEQ + i0) * HD;
    const int n = wave * 16 + lr;
#pragma unroll
    for (int db = 0; db < 4; db++) {
      uint2 pw;
      pw.x = cvtpk(ao[db][0], ao[db][1]);
      pw.y = cvtpk(ao[db][2], ao[db][3]);
      *(uint2*)(Upart + base + (size_t)n * HD + db * 16 + lg * 4) = pw;
    }
    if (lg == 0) {
      mpart[((size_t)z * NHEAD + h) * SEQ + i0 + n] = m_i;
      lpart[((size_t)z * NHEAD + h) * SEQ + i0 + n] = l_i;
    }
  }
}

// ---------------------------------------------------------------- K3: combine + out-projection
// 32x64-tile GEMM (BK=64, 512 blocks = 2/CU) out = AO * opw^T + opb; AO combined on the
// fly from JSPLIT bf16 partials. T1 XCD grouping: XCD X owns m-tiles [8X,8X+8).
__global__ __launch_bounds__(256) void combine_outproj(
    const u16* __restrict__ Upart, const float* __restrict__ mpart,
    const float* __restrict__ lpart, const float* __restrict__ opw,
    const float* __restrict__ opb, float* __restrict__ out)
{
  __shared__ u16 As[32][72];
  __shared__ u16 Bs[64][72];
  __shared__ float cww[JSPLIT][NHEAD][32];

  const int t = threadIdx.x;
  // XCD-grouped (bijective): X = b%8, j = b/8; mt = 8X + (j>>3), nt = j&7
  const int b = blockIdx.x;
  const int X = b & 7, jb = b >> 3;
  const int mt = X * 8 + (jb >> 3), nt = jb & 7;
  const int m0 = mt * 32, n0 = nt * 64;

  // combine weights per (h, local row): 8 heads x 32 rows = 256 -> one per thread
  {
    const int hh = t >> 5, nl = t & 31;
    const int gn = m0 + nl;
    float mz[JSPLIT], wz[JSPLIT];
    float M = -1e30f;
#pragma unroll
    for (int zz = 0; zz < JSPLIT; zz++) {
      mz[zz] = mpart[((size_t)zz * NHEAD + hh) * SEQ + gn];
      M = fmaxf(M, mz[zz]);
    }
    float Ls = 0.f;
#pragma unroll
    for (int zz = 0; zz < JSPLIT; zz++) {
      wz[zz] = exp2f(mz[zz] - M);
      Ls += wz[zz] * lpart[((size_t)zz * NHEAD + hh) * SEQ + gn];
    }
    const float inv = 1.0f / Ls;
#pragma unroll
    for (int zz = 0; zz < JSPLIT; zz++) cww[zz][hh][nl] = wz[zz] * inv;
  }
  __syncthreads();

  const int w = t >> 6, lane = t & 63, lr = lane & 15, lg = lane >> 4;
  const int arow = t >> 3, akb = (t & 7) * 8;     // A staging: 32 rows x 64 k
  const int brow = t >> 2, bkb = (t & 3) * 16;    // B staging: 64 rows x 64 k

  float4v acc[2];
#pragma unroll
  for (int mi = 0; mi < 2; mi++) acc[mi] = (float4v){0.f, 0.f, 0.f, 0.f};

  const float* pw = opw + (size_t)(n0 + brow) * EMB + bkb;

  int hcur = akb >> 6, dcur = akb & 63;
  uint4 ua[JSPLIT];
#pragma unroll
  for (int zz = 0; zz < JSPLIT; zz++)
    ua[zz] = *(const uint4*)(Upart + (((size_t)zz * NHEAD + hcur) * SEQ + m0 + arow) * HD + dcur);
  float4 bbv[4];
#pragma unroll
  for (int j = 0; j < 4; j++) bbv[j] = *(const float4*)(pw + j * 4);

  for (int k0 = 0; k0 < EMB; k0 += 64) {
    // combine -> bf16 A tile (8 elems/thread)
    {
      float cc[8];
#pragma unroll
      for (int j = 0; j < 8; j++) cc[j] = 0.f;
#pragma unroll
      for (int zz = 0; zz < JSPLIT; zz++) {
        const float wgt = cww[zz][hcur][arow];
        F8 q0; q0.u4 = ua[zz];
#pragma unroll
        for (int j = 0; j < 8; j++) cc[j] += wgt * bf2f((u16)q0.us[j]);
      }
      float4 c0 = {cc[0], cc[1], cc[2], cc[3]}, c1 = {cc[4], cc[5], cc[6], cc[7]};
      *(uint4*)&As[arow][akb] = pk8(c0, c1);
      *(uint4*)&Bs[brow][bkb]     = pk8(bbv[0], bbv[1]);
      *(uint4*)&Bs[brow][bkb + 8] = pk8(bbv[2], bbv[3]);
    }
    __syncthreads();
    if (k0 + 64 < EMB) {                          // prefetch next K-tile
      const int e = k0 + 64 + akb;
      hcur = e >> 6; dcur = e & 63;
#pragma unroll
      for (int zz = 0; zz < JSPLIT; zz++)
        ua[zz] = *(const uint4*)(Upart + (((size_t)zz * NHEAD + hcur) * SEQ + m0 + arow) * HD + dcur);
#pragma unroll
      for (int j = 0; j < 4; j++) bbv[j] = *(const float4*)(pw + k0 + 64 + j * 4);
    }
    F8 af[2][2], bf_[2];
#pragma unroll
    for (int kc = 0; kc < 2; kc++) {
#pragma unroll
      for (int mi = 0; mi < 2; mi++)
        af[mi][kc].u4 = *(const uint4*)&As[mi * 16 + lr][kc * 32 + lg * 8];
      bf_[kc].u4 = *(const uint4*)&Bs[w * 16 + lr][kc * 32 + lg * 8];
    }
#pragma unroll
    for (int kc = 0; kc < 2; kc++)
#pragma unroll
      for (int mi = 0; mi < 2; mi++)
        acc[mi] = __builtin_amdgcn_mfma_f32_16x16x32_bf16(af[mi][kc].v, bf_[kc].v, acc[mi], 0, 0, 0);
    __syncthreads();
  }

  const int n = n0 + w * 16 + lr;
  const float bias = opb[n];
#pragma unroll
  for (int mi = 0; mi < 2; mi++) {
    const int mb = m0 + mi * 16 + lg * 4;
#pragma unroll
    for (int r = 0; r < 4; r++)
      out[(size_t)(mb + r) * EMB + n] = acc[mi][r] + bias;
  }
}

// ---------------------------------------------------------------- launcher
extern "C" void kernel_launch(void* const* d_in, const int* in_sizes, int n_in,
                              void* d_out, int out_size, void* d_ws, size_t ws_size,
                              hipStream_t stream)
{
  const float* query = (const float*)d_in[0];
  const float* key_  = (const float*)d_in[1];
  const float* value = (const float*)d_in[2];
  const int*   eid   = (const int*)d_in[3];
  const float* ipw   = (const float*)d_in[4];
  const float* ipb   = (const float*)d_in[5];
  const float* opw   = (const float*)d_in[6];
  const float* opb   = (const float*)d_in[7];
  const float* ek    = (const float*)d_in[8];
  float* out = (float*)d_out;

  char* ws = (char*)d_ws;
  u16* Qs = (u16*)ws;              ws += (size_t)NHEAD * SEQ * HD * 2;
  u16* Kb = (u16*)ws;              ws += (size_t)NHEAD * SEQ * HD * 2;
  u16* Vb = (u16*)ws;              ws += (size_t)NHEAD * SEQ * HD * 2;     // transposed [h][d][j]
  unsigned* eidp = (unsigned*)ws;  ws += (size_t)SEQ * SEQ;                // u8-packed as u32
  u16* Upart = (u16*)ws;           ws += (size_t)JSPLIT * NHEAD * SEQ * HD * 2;  // bf16 partials
  float* mpart = (float*)ws;       ws += (size_t)JSPLIT * NHEAD * SEQ * 4;
  float* lpart = (float*)ws;       ws += (size_t)JSPLIT * NHEAD * SEQ * 4;

  fused_prep_gemm<<<dim3(QKV_BLOCKS + PACK_BLOCKS), dim3(256), 0, stream>>>(
      query, key_, value, ipw, ipb, eid, Qs, Kb, Vb, eidp);
  attn_kernel<<<dim3(SEQ / 64 * NHEAD * JSPLIT), dim3(256), 0, stream>>>(
      Qs, Kb, Vb, eidp, ek, Upart, mpart, lpart);
  combine_outproj<<<dim3((SEQ / 32) * (EMB / 64)), dim3(256), 0, stream>>>(
      Upart, mpart, lpart, opw, opb, out);
}